// Round 1
// baseline (1186.332 us; speedup 1.0000x reference)
//
#include <hip/hip_runtime.h>

#define BLOCK 512
#define WAVES_PER_BLOCK (BLOCK / 64)
#define E 2  // examples per wave per chunk

__device__ __forceinline__ float tanh_fast(float x) {
    // 1 - 2/(e^{2x}+1): correct limits at +-inf, ~1e-6 rel error
    float e = __expf(2.0f * x);
    return 1.0f - 2.0f / (e + 1.0f);
}

__global__ __launch_bounds__(BLOCK, 1) void pinn_kernel(
    const float* __restrict__ x,
    const float* __restrict__ W1, const float* __restrict__ b1,
    const float* __restrict__ W2, const float* __restrict__ b2,
    const float* __restrict__ W3, const float* __restrict__ b3,
    const float* __restrict__ W4, const float* __restrict__ b4,
    float* __restrict__ out, int N)
{
    __shared__ float w1s[384];          // [3][128]
    __shared__ float b1s[128];
    __shared__ float w2s[128 * 128];    // [k][j]
    __shared__ float b2s[128];
    __shared__ float w3s[128 * 64];     // [k][j]
    __shared__ float b3s[64];
    __shared__ float w4s[64];
    __shared__ float4 bcast[WAVES_PER_BLOCK][E][128];  // {h, dz, dt, d2z} per unit

    // ---- stage weights to LDS ----
    for (int i = threadIdx.x; i < 128 * 128; i += BLOCK) w2s[i] = W2[i];
    for (int i = threadIdx.x; i < 128 * 64; i += BLOCK) w3s[i] = W3[i];
    for (int i = threadIdx.x; i < 384; i += BLOCK) w1s[i] = W1[i];
    for (int i = threadIdx.x; i < 128; i += BLOCK) { b1s[i] = b1[i]; b2s[i] = b2[i]; }
    for (int i = threadIdx.x; i < 64; i += BLOCK) { b3s[i] = b3[i]; w4s[i] = W4[i]; }
    __syncthreads();

    const int lane = threadIdx.x & 63;
    const int wave = threadIdx.x >> 6;
    const int gwave = blockIdx.x * WAVES_PER_BLOCK + wave;
    const int nwaves = gridDim.x * WAVES_PER_BLOCK;
    const float b4v = b4[0];

    const int nchunk = N / E;  // N divisible by E
    for (int chunk = gwave; chunk < nchunk; chunk += nwaves) {
        const int ebase = chunk * E;

        // ---- layer 1 (3 -> 128) ----
        for (int e = 0; e < E; e++) {
            int ei = ebase + e;
            float x0 = x[3 * ei + 0], x1 = x[3 * ei + 1], x2 = x[3 * ei + 2];
#pragma unroll
            for (int r = 0; r < 2; r++) {
                int u = lane + 64 * r;
                float az = w1s[u];         // dz1/ds = W1[0][u]
                float at = w1s[128 + u];   // dz1/dt = W1[1][u]
                float z = x0 * az + x1 * at + x2 * w1s[256 + u] + b1s[u];
                float h = tanh_fast(z);
                float g = 1.0f - h * h;
                float ah = g * az;
                float th = g * at;
                float ch = -2.0f * h * g * az * az;  // z''=0 into layer 1
                bcast[wave][e][u] = make_float4(h, ah, th, ch);
            }
        }

        // ---- layer 2 (128 -> 128) ----
        float v[E][2], a[E][2], t[E][2], c[E][2];
#pragma unroll
        for (int e = 0; e < E; e++)
#pragma unroll
            for (int r = 0; r < 2; r++) {
                v[e][r] = b2s[lane + 64 * r];
                a[e][r] = 0.f; t[e][r] = 0.f; c[e][r] = 0.f;
            }
#pragma unroll 4
        for (int k = 0; k < 128; k++) {
            float w0 = w2s[k * 128 + lane];
            float w1v = w2s[k * 128 + lane + 64];
#pragma unroll
            for (int e = 0; e < E; e++) {
                float4 hb = bcast[wave][e][k];
                v[e][0] += hb.x * w0; v[e][1] += hb.x * w1v;
                a[e][0] += hb.y * w0; a[e][1] += hb.y * w1v;
                t[e][0] += hb.z * w0; t[e][1] += hb.z * w1v;
                c[e][0] += hb.w * w0; c[e][1] += hb.w * w1v;
            }
        }
#pragma unroll
        for (int e = 0; e < E; e++)
#pragma unroll
            for (int r = 0; r < 2; r++) {
                float h = tanh_fast(v[e][r]);
                float g = 1.0f - h * h;
                float ah = g * a[e][r];
                float th = g * t[e][r];
                float ch = g * c[e][r] - 2.0f * h * g * a[e][r] * a[e][r];
                bcast[wave][e][lane + 64 * r] = make_float4(h, ah, th, ch);
            }

        // ---- layer 3 (128 -> 64) ----
        float v3[E], a3[E], t3[E], c3[E];
#pragma unroll
        for (int e = 0; e < E; e++) { v3[e] = b3s[lane]; a3[e] = 0.f; t3[e] = 0.f; c3[e] = 0.f; }
#pragma unroll 4
        for (int k = 0; k < 128; k++) {
            float w = w3s[k * 64 + lane];
#pragma unroll
            for (int e = 0; e < E; e++) {
                float4 hb = bcast[wave][e][k];
                v3[e] += hb.x * w; a3[e] += hb.y * w; t3[e] += hb.z * w; c3[e] += hb.w * w;
            }
        }

        // ---- layer 4 (64 -> 1) + wave reduction ----
        float w4v = w4s[lane];
#pragma unroll
        for (int e = 0; e < E; e++) {
            float h = tanh_fast(v3[e]);
            float g = 1.0f - h * h;
            float pT = h * w4v;
            float pA = (g * a3[e]) * w4v;
            float pt = (g * t3[e]) * w4v;
            float pc = (g * c3[e] - 2.0f * h * g * a3[e] * a3[e]) * w4v;
#pragma unroll
            for (int off = 32; off >= 1; off >>= 1) {
                pT += __shfl_xor(pT, off);
                pA += __shfl_xor(pA, off);
                pt += __shfl_xor(pt, off);
                pc += __shfl_xor(pc, off);
            }
            if (lane == 0) {
                int ei = ebase + e;
                if (ei < N) {
                    out[4 * ei + 0] = pT + b4v;
                    out[4 * ei + 1] = pA;
                    out[4 * ei + 2] = pt;
                    out[4 * ei + 3] = pc;
                }
            }
        }
    }
}

extern "C" void kernel_launch(void* const* d_in, const int* in_sizes, int n_in,
                              void* d_out, int out_size, void* d_ws, size_t ws_size,
                              hipStream_t stream) {
    const float* x  = (const float*)d_in[0];
    const float* W1 = (const float*)d_in[1];
    const float* b1 = (const float*)d_in[2];
    const float* W2 = (const float*)d_in[3];
    const float* b2 = (const float*)d_in[4];
    const float* W3 = (const float*)d_in[5];
    const float* b3 = (const float*)d_in[6];
    const float* W4 = (const float*)d_in[7];
    const float* b4 = (const float*)d_in[8];
    float* out = (float*)d_out;
    int N = in_sizes[0] / 3;

    dim3 grid(256), block(BLOCK);
    hipLaunchKernelGGL(pinn_kernel, grid, block, 0, stream,
                       x, W1, b1, W2, b2, W3, b3, W4, b4, out, N);
}

// Round 2
// 220.415 us; speedup vs baseline: 5.3823x; 5.3823x over previous
//
#include <hip/hip_runtime.h>

typedef __attribute__((ext_vector_type(8))) short short8;
typedef __attribute__((ext_vector_type(4))) float f32x4;
typedef unsigned short u16;
typedef unsigned int u32;

#define BLOCK 384
#define WPB 6            // waves per block
#define GRID 256
#define KP 136           // padded row stride in ushorts (128 + 8)

// dynamic-LDS byte offsets (all 16B aligned)
#define OFF_W2 0         // 128x136 bf16 = 34816 B  (W2^T: [n][k])
#define OFF_W3 34816     // 64x136 bf16 = 17408 B   (W3^T: [n][k])
#define OFF_W1 52224     // 128 float4 {az,at,aw,b1} = 2048 B
#define OFF_B2 54272     // 128 f32
#define OFF_B3 54784     // 64 f32
#define OFF_W4 55040     // 64 f32
#define OFF_HS 55296     // per-wave staging: 4 streams x 16 x 136 bf16
#define HS_BYTES 17408
#define LDS_TOTAL 159744

__device__ __forceinline__ float tanh_fast(float x) {
    float e = __expf(2.0f * x);
    return 1.0f - 2.0f / (e + 1.0f);   // exact at +-inf
}
__device__ __forceinline__ u16 f2bf(float f) {   // RNE fp32 -> bf16
    u32 u = __float_as_uint(f);
    return (u16)((u + 0x7fffu + ((u >> 16) & 1u)) >> 16);
}
#define MFMA16(acc, a, b) acc = __builtin_amdgcn_mfma_f32_16x16x32_bf16(a, b, acc, 0, 0, 0)

__global__ __launch_bounds__(BLOCK, 1) void pinn_mfma(
    const float* __restrict__ x,
    const float* __restrict__ W1, const float* __restrict__ b1,
    const float* __restrict__ W2, const float* __restrict__ b2,
    const float* __restrict__ W3, const float* __restrict__ b3,
    const float* __restrict__ W4, const float* __restrict__ b4,
    float* __restrict__ out, int N)
{
    extern __shared__ char smem[];
    u16*    w2t = (u16*)(smem + OFF_W2);
    u16*    w3t = (u16*)(smem + OFF_W3);
    float4* w1s = (float4*)(smem + OFF_W1);
    float*  b2s = (float*)(smem + OFF_B2);
    float*  b3s = (float*)(smem + OFF_B3);
    float*  w4s = (float*)(smem + OFF_W4);

    // ---- stage weights (bf16, transposed N-major for B-frag reads) ----
    for (int i = threadIdx.x; i < 128 * 128; i += BLOCK) {
        int k = i >> 7, n = i & 127;
        w2t[n * KP + k] = f2bf(W2[i]);
    }
    for (int i = threadIdx.x; i < 128 * 64; i += BLOCK) {
        int k = i >> 6, n = i & 63;
        w3t[n * KP + k] = f2bf(W3[i]);
    }
    for (int j = threadIdx.x; j < 128; j += BLOCK) {
        w1s[j] = make_float4(W1[j], W1[128 + j], W1[256 + j], b1[j]);
        b2s[j] = b2[j];
    }
    for (int j = threadIdx.x; j < 64; j += BLOCK) {
        b3s[j] = b3[j];
        w4s[j] = W4[j];
    }
    __syncthreads();

    const int lane = threadIdx.x & 63;
    const int wv = threadIdx.x >> 6;
    const int q = lane >> 4;     // quad 0..3
    const int e = lane & 15;     // 0..15
    u16* hs = (u16*)(smem + OFF_HS + wv * HS_BYTES);  // [stream][16][KP]
    const float b4v = b4[0];

    const int ntiles = N >> 4;
    const int gw = blockIdx.x * WPB + wv;
    const int nw = gridDim.x * WPB;

    for (int tile = gw; tile < ntiles; tile += nw) {
        const int gbase = tile << 4;

        // ================= layer 1 (3 -> 128), fp32 VALU =================
        {
            const float* xp = x + 3 * (size_t)(gbase + e);
            float x0 = xp[0], x1 = xp[1], x2 = xp[2];
#pragma unroll
            for (int blk = 0; blk < 4; blk++) {
                short8 pv, pa, pt, pc;
#pragma unroll
                for (int jj = 0; jj < 8; jj++) {
                    int j = q * 32 + blk * 8 + jj;
                    float4 w = w1s[j];  // {W1[0][j], W1[1][j], W1[2][j], b1[j]}
                    float z = fmaf(x0, w.x, fmaf(x1, w.y, fmaf(x2, w.z, w.w)));
                    float h = tanh_fast(z);
                    float g = 1.0f - h * h;
                    pv[jj] = (short)f2bf(h);
                    pa[jj] = (short)f2bf(g * w.x);                       // dz tangent
                    pt[jj] = (short)f2bf(g * w.y);                       // dt tangent
                    pc[jj] = (short)f2bf(-2.0f * h * g * w.x * w.x);     // d2z tangent
                }
                int col = q * 32 + blk * 8;
                *(short8*)&hs[(0 * 16 + e) * KP + col] = pv;
                *(short8*)&hs[(1 * 16 + e) * KP + col] = pa;
                *(short8*)&hs[(2 * 16 + e) * KP + col] = pt;
                *(short8*)&hs[(3 * 16 + e) * KP + col] = pc;
            }
        }

        // ================= layer 2 (128 -> 128), MFMA =================
        short8 A2[4][4];  // [stream][kfrag]
#pragma unroll
        for (int s = 0; s < 4; s++)
#pragma unroll
            for (int kf = 0; kf < 4; kf++)
                A2[s][kf] = *(const short8*)&hs[(s * 16 + e) * KP + kf * 32 + q * 8];

#pragma unroll
        for (int nt = 0; nt < 8; nt++) {
            const u16* wrow = &w2t[(nt * 16 + e) * KP + q * 8];
            float bias = b2s[nt * 16 + e];
            f32x4 av = {bias, bias, bias, bias};
            f32x4 aa = {0.f, 0.f, 0.f, 0.f};
            f32x4 at_ = {0.f, 0.f, 0.f, 0.f};
            f32x4 ac = {0.f, 0.f, 0.f, 0.f};
#pragma unroll
            for (int kf = 0; kf < 4; kf++) {
                short8 B = *(const short8*)&wrow[kf * 32];
                MFMA16(av, A2[0][kf], B);
                MFMA16(aa, A2[1][kf], B);
                MFMA16(at_, A2[2][kf], B);
                MFMA16(ac, A2[3][kf], B);
            }
            // epilogue: tanh chain in C-layout, write next layer's A (bf16)
#pragma unroll
            for (int r = 0; r < 4; r++) {
                float h = tanh_fast(av[r]);
                float g = 1.0f - h * h;
                float na = g * aa[r];
                float ntv = g * at_[r];
                float nc = g * ac[r] - 2.0f * h * g * aa[r] * aa[r];
                int m = q * 4 + r, k = nt * 16 + e;
                hs[(0 * 16 + m) * KP + k] = f2bf(h);
                hs[(1 * 16 + m) * KP + k] = f2bf(na);
                hs[(2 * 16 + m) * KP + k] = f2bf(ntv);
                hs[(3 * 16 + m) * KP + k] = f2bf(nc);
            }
        }

        // ================= layer 3 (128 -> 64), MFMA =================
        short8 A3[4][4];
#pragma unroll
        for (int s = 0; s < 4; s++)
#pragma unroll
            for (int kf = 0; kf < 4; kf++)
                A3[s][kf] = *(const short8*)&hs[(s * 16 + e) * KP + kf * 32 + q * 8];

        f32x4 v3[4], a3[4], t3[4], c3[4];
#pragma unroll
        for (int nt = 0; nt < 4; nt++) {
            const u16* wrow = &w3t[(nt * 16 + e) * KP + q * 8];
            float bias = b3s[nt * 16 + e];
            v3[nt] = (f32x4){bias, bias, bias, bias};
            a3[nt] = (f32x4){0.f, 0.f, 0.f, 0.f};
            t3[nt] = (f32x4){0.f, 0.f, 0.f, 0.f};
            c3[nt] = (f32x4){0.f, 0.f, 0.f, 0.f};
#pragma unroll
            for (int kf = 0; kf < 4; kf++) {
                short8 B = *(const short8*)&wrow[kf * 32];
                MFMA16(v3[nt], A3[0][kf], B);
                MFMA16(a3[nt], A3[1][kf], B);
                MFMA16(t3[nt], A3[2][kf], B);
                MFMA16(c3[nt], A3[3][kf], B);
            }
        }

        // ================= layer 4 (64 -> 1) + reduce + store =================
        float rT[4], rA[4], rTt[4], rC[4];
#pragma unroll
        for (int r = 0; r < 4; r++) {
            float sT = 0.f, sA = 0.f, sTt = 0.f, sC = 0.f;
#pragma unroll
            for (int nt = 0; nt < 4; nt++) {
                float w4v = w4s[nt * 16 + e];
                float h = tanh_fast(v3[nt][r]);
                float g = 1.0f - h * h;
                sT = fmaf(h, w4v, sT);
                sA = fmaf(g * a3[nt][r], w4v, sA);
                sTt = fmaf(g * t3[nt][r], w4v, sTt);
                sC = fmaf(g * c3[nt][r] - 2.0f * h * g * a3[nt][r] * a3[nt][r], w4v, sC);
            }
#pragma unroll
            for (int off = 1; off < 16; off <<= 1) {
                sT += __shfl_xor(sT, off);
                sA += __shfl_xor(sA, off);
                sTt += __shfl_xor(sTt, off);
                sC += __shfl_xor(sC, off);
            }
            rT[r] = sT; rA[r] = sA; rTt[r] = sTt; rC[r] = sC;
        }
        if (e < 4) {
            int m = q * 4 + e;
            float oT  = (e & 2) ? ((e & 1) ? rT[3]  : rT[2])  : ((e & 1) ? rT[1]  : rT[0]);
            float oA  = (e & 2) ? ((e & 1) ? rA[3]  : rA[2])  : ((e & 1) ? rA[1]  : rA[0]);
            float oTt = (e & 2) ? ((e & 1) ? rTt[3] : rTt[2]) : ((e & 1) ? rTt[1] : rTt[0]);
            float oC  = (e & 2) ? ((e & 1) ? rC[3]  : rC[2])  : ((e & 1) ? rC[1]  : rC[0]);
            float4 o = make_float4(oT + b4v, oA, oTt, oC);
            *(float4*)(out + 4 * (size_t)(gbase + m)) = o;
        }
    }
}

extern "C" void kernel_launch(void* const* d_in, const int* in_sizes, int n_in,
                              void* d_out, int out_size, void* d_ws, size_t ws_size,
                              hipStream_t stream) {
    const float* x  = (const float*)d_in[0];
    const float* W1 = (const float*)d_in[1];
    const float* b1 = (const float*)d_in[2];
    const float* W2 = (const float*)d_in[3];
    const float* b2 = (const float*)d_in[4];
    const float* W3 = (const float*)d_in[5];
    const float* b3 = (const float*)d_in[6];
    const float* W4 = (const float*)d_in[7];
    const float* b4 = (const float*)d_in[8];
    float* out = (float*)d_out;
    int N = in_sizes[0] / 3;

    (void)hipFuncSetAttribute((const void*)pinn_mfma,
                              hipFuncAttributeMaxDynamicSharedMemorySize, LDS_TOTAL);
    hipLaunchKernelGGL(pinn_mfma, dim3(GRID), dim3(BLOCK), LDS_TOTAL, stream,
                       x, W1, b1, W2, b2, W3, b3, W4, b4, out, N);
}